// Round 8
// baseline (272.161 us; speedup 1.0000x reference)
//
#include <hip/hip_runtime.h>
#include <hip/hip_bf16.h>

// LocallyConnected2d: y[b,o,h,w] = bias[o,h,w] +
//   sum_{i,kh,kw} xpad[b,i,h+kh,w+kw] * weight[i,o,h,w,kh,kw]
// B=64, CIN=COUT=64, H=W=32, K=3, pad=1, fp32 in/out.
// Round 13: o-QUARTER split for TLP. Round-12 (verified, barrier-free,
// per-lane B loads) is latency-bound at 2 blocks/CU with everything idle
// (VALU 5.9%, Mfma 1.9%, HBM 14%); grid was the occupancy limiter.
// Now: 1024 blocks = 4 locs x 16 o's each -> 4 blocks/CU, 16 waves/CU.
// Per chunk per wave: 1 B-frag (3 loads), 4 MFMA; Bs drops nt dim (8 KB);
// LDS 25 KB. All mappings verbatim from verified round 12 with nt removed.

#define B_    64
#define HW_   32
#define HP_   34
#define NLOC  1024
#define W_OST 9216u     // floats per o step
#define W_IST 589824u   // floats per i step
#define XT_BYTES  ((size_t)64*HP_*HP_*64*2)          //  9,469,952
#define WS_NEED   (XT_BYTES)
#define SCR_R 528       // shorts per role stripe: 512 + 16 pad (bank spread)

typedef __attribute__((ext_vector_type(8))) short short8;
typedef __attribute__((ext_vector_type(8))) unsigned short ushort8;
typedef __attribute__((ext_vector_type(4))) float floatx4;

static __device__ __forceinline__ unsigned short f2bf(float f) {
  __hip_bfloat16 h = __float2bfloat16(f);   // RNE
  return __builtin_bit_cast(unsigned short, h);
}

// unaligned-tolerant float4 load (weight rows are only 4B-aligned: loc*36B)
static __device__ __forceinline__ floatx4 ldf4u(const float* p) {
  floatx4 v; __builtin_memcpy(&v, p, 16); return v;
}

// ---------------------------------------------------------------------------
// Kernel 1: pad+transpose x[b][i][h][w] (fp32) -> xt[i][hh][ww][b] (bf16).
// (verified rounds 2-12, unchanged)
// ---------------------------------------------------------------------------
__global__ __launch_bounds__(256) void xpose_pad(const float* __restrict__ x,
                                                 unsigned short* __restrict__ xt) {
  int bid = blockIdx.x;                 // 64*34
  int i = bid / HP_, hh = bid % HP_;
  __shared__ float tile[B_ * 33];
  int t = threadIdx.x;
  bool interior = (hh >= 1 && hh <= HW_);
  if (interior) {
    int h = hh - 1, w = t & 31, bs = t >> 5;
    #pragma unroll
    for (int r = 0; r < 8; ++r) {
      int b = r * 8 + bs;
      tile[b * 33 + w] = x[(((size_t)b * 64 + i) * HW_ + h) * HW_ + w];
    }
  }
  __syncthreads();
  int b = t & 63, wsb = t >> 6;
  size_t base = (size_t)(i * HP_ + hh) * HP_ * B_;
  #pragma unroll
  for (int s = 0; s < 9; ++s) {
    int ww = s * 4 + wsb;
    if (ww < HP_) {
      float v = 0.f;
      if (interior && ww >= 1 && ww <= HW_) v = tile[b * 33 + (ww - 1)];
      xt[base + (size_t)ww * B_ + b] = f2bf(v);
    }
  }
}

// ---------------------------------------------------------------------------
// Kernel 2: fused im2col + GEMM, o-quarter split, direct per-lane B loads.
// Block = 4 consecutive locs x 16 o's, 256 thr = 4 waves; wave = ll (loc).
// LDS: Bs 8K + scr4 16.9K = 24.9K. Wave-private only; no barriers.
// ---------------------------------------------------------------------------
__global__ __launch_bounds__(256, 2) void lc2d_fused(
    const unsigned short* __restrict__ xt,
    const float* __restrict__ wsrc,
    const float* __restrict__ bias,
    float* __restrict__ out) {
  __shared__ __align__(16) unsigned short Bs[8 * 64 * 8];      // 8 KB (kk=8)
  __shared__ __align__(16) unsigned short scr4[4][4 * SCR_R];  // 16.9 KB

  const int bid   = blockIdx.x;                    // 1024 blocks
  const int lt    = ((bid & 7) << 7) | (bid >> 3); // XCD-grouped tile id
  const int oq    = lt & 3;                        // o-quarter 0..3
  const int loc0  = (lt >> 2) << 2;                // loc0 % 4 == 0
  const int tid   = threadIdx.x;
  const int lane  = tid & 63;
  const int ll    = tid >> 6;                      // wave = loc index 0..3
  const int loc   = loc0 + ll;
  const int hblk  = loc >> 5, wblk = loc & 31;
  const int col   = lane & 15;
  const int quad  = lane >> 4;
  const int o_0   = oq * 16 + col;

  floatx4 acc[4];
  {
    float b0 = bias[(unsigned)o_0 * 1024u + (unsigned)loc];
    #pragma unroll
    for (int mt = 0; mt < 4; ++mt) acc[mt] = (floatx4){b0, b0, b0, b0};
  }

  // ---- B side: per-lane direct loads. Lane's row base:
  //      w[i][o_0][loc][*] with i = 4c+quad.
  const unsigned bbase0 = (unsigned)quad * W_IST + (unsigned)o_0 * W_OST
                        + (unsigned)loc * 9u;
  auto loadB = [&](int c, floatx4 &fa, floatx4 &fb, float &s) {
    unsigned off = bbase0 + (unsigned)(4 * c) * W_IST;
    fa = ldf4u(wsrc + off);
    fb = ldf4u(wsrc + off + 4);
    s  = wsrc[off + 8];
  };
  auto cvtB = [&](floatx4 fa, floatx4 fb) -> ushort8 {
    ushort8 r;
    r[0] = f2bf(fa[0]); r[1] = f2bf(fa[1]); r[2] = f2bf(fa[2]); r[3] = f2bf(fa[3]);
    r[4] = f2bf(fb[0]); r[5] = f2bf(fb[1]); r[6] = f2bf(fb[2]); r[7] = f2bf(fb[3]);
    return r;
  };
  // kk=8 stash write (verified round-12 layout with nt dim dropped)
  auto stashB = [&](int c, float s) {
    int sc = c >> 3, cpr = c & 7;
    int sub = (cpr >> 1) * 16 + col;          // (k2>>3)*16 + oc
    int el  = (cpr & 1) * 4 + quad;           // k2 & 7
    Bs[((ll * 2 + sc) * 64 + sub) * 8 + el] = f2bf(s);
  };

  // ---- A side: xt load + 4-role scr + direct reg gather (verified r10-r12)
  auto xtLoad = [&](int t, int q) -> ushort8 {
    int i, kh, kw;
    if (t < 16) {
      i = (t << 2) + q;
      int kk = lane >> 3;                      // 0..7
      kh = kk / 3; kw = kk - kh * 3;
    } else {
      i = ((t - 16) << 5) + (q << 3) + (lane >> 3);
      kh = 2; kw = 2;
    }
    return *(const ushort8*)(xt +
        (((unsigned)i * HP_ + (unsigned)(hblk + kh)) * HP_ + (unsigned)(wblk + kw)) * 64u
        + ((unsigned)(lane & 7) << 3));
  };
  auto buildA = [&](ushort8 v0, ushort8 v1, ushort8 v2, ushort8 v3,
                    ushort8 &a0, ushort8 &a1, ushort8 &a2, ushort8 &a3) {
    *(ushort8*)&scr4[ll][0 * SCR_R + (lane << 3)] = v0;
    *(ushort8*)&scr4[ll][1 * SCR_R + (lane << 3)] = v1;
    *(ushort8*)&scr4[ll][2 * SCR_R + (lane << 3)] = v2;
    *(ushort8*)&scr4[ll][3 * SCR_R + (lane << 3)] = v3;
    __asm__ volatile("s_waitcnt lgkmcnt(0)" ::: "memory");
    const int rb = (lane >> 4) * SCR_R + (lane & 15);
    #pragma unroll
    for (int j = 0; j < 8; ++j) {
      a0[j] = scr4[ll][rb + j * 64 +  0];
      a1[j] = scr4[ll][rb + j * 64 + 16];
      a2[j] = scr4[ll][rb + j * 64 + 32];
      a3[j] = scr4[ll][rb + j * 64 + 48];
    }
  };

  // ---- MFMA: 4 A-frags x 1 B-frag (same call order as verified)
  auto doMFMA = [&](ushort8 a0, ushort8 a1, ushort8 a2, ushort8 a3, ushort8 b0) {
    acc[0] = __builtin_amdgcn_mfma_f32_16x16x32_bf16(
        __builtin_bit_cast(short8, a0), __builtin_bit_cast(short8, b0), acc[0], 0, 0, 0);
    acc[1] = __builtin_amdgcn_mfma_f32_16x16x32_bf16(
        __builtin_bit_cast(short8, a1), __builtin_bit_cast(short8, b0), acc[1], 0, 0, 0);
    acc[2] = __builtin_amdgcn_mfma_f32_16x16x32_bf16(
        __builtin_bit_cast(short8, a2), __builtin_bit_cast(short8, b0), acc[2], 0, 0, 0);
    acc[3] = __builtin_amdgcn_mfma_f32_16x16x32_bf16(
        __builtin_bit_cast(short8, a3), __builtin_bit_cast(short8, b0), acc[3], 0, 0, 0);
  };

  // ---- prologue: chunk 0 inputs in flight
  floatx4 cfa, cfb; float cs;                 // current B
  floatx4 nfa, nfb; float ns;                 // next B
  loadB(0, cfa, cfb, cs);
  ushort8 xv0 = xtLoad(0, 0), xv1 = xtLoad(0, 1);
  ushort8 xv2 = xtLoad(0, 2), xv3 = xtLoad(0, 3);

  // ---- main loop c = 0..15 (no barriers; depth-1 prefetch of B and xt)
  #pragma unroll 1
  for (int c = 0; c < 16; ++c) {
    ushort8 nx0 = xtLoad(c + 1, 0), nx1 = xtLoad(c + 1, 1);
    ushort8 nx2 = xtLoad(c + 1, 2), nx3 = xtLoad(c + 1, 3);
    if (c < 15) loadB(c + 1, nfa, nfb, ns);
    ushort8 b0 = cvtB(cfa, cfb);
    stashB(c, cs);
    ushort8 a0, a1, a2, a3;
    buildA(xv0, xv1, xv2, xv3, a0, a1, a2, a3);
    doMFMA(a0, a1, a2, a3, b0);
    cfa = nfa; cfb = nfb; cs = ns;
    xv0 = nx0; xv1 = nx1; xv2 = nx2; xv3 = nx3;
  }

  // ---- stash chunks (kk=8): c = 16, 17; B from Bs (wave-private RAW,
  //      ordered by lgkmcnt — no barrier needed)
  __asm__ volatile("s_waitcnt lgkmcnt(0)" ::: "memory");
  {
    ushort8 nx0 = xtLoad(17, 0), nx1 = xtLoad(17, 1);
    ushort8 nx2 = xtLoad(17, 2), nx3 = xtLoad(17, 3);
    ushort8 a0, a1, a2, a3;
    buildA(xv0, xv1, xv2, xv3, a0, a1, a2, a3);
    {
      ushort8 b0 = *(const ushort8*)(&Bs[0] + (size_t)(((ll << 1) + 0) * 64 + lane) * 8);
      doMFMA(a0, a1, a2, a3, b0);                              // sc=0
    }
    buildA(nx0, nx1, nx2, nx3, a0, a1, a2, a3);
    {
      ushort8 b0 = *(const ushort8*)(&Bs[0] + (size_t)(((ll << 1) + 1) * 64 + lane) * 8);
      doMFMA(a0, a1, a2, a3, b0);                              // sc=1
    }
  }

  // ---- epilogue: D mapping col=o=lane&15, row=b = mt*16 + quad*4 + r (verified)
  #pragma unroll
  for (int mt = 0; mt < 4; ++mt) {
    int b = mt * 16 + quad * 4;
    #pragma unroll
    for (int r = 0; r < 4; ++r) {
      out[((unsigned)(b + r) * 64u + (unsigned)o_0) * 1024u + (unsigned)loc] = acc[mt][r];
    }
  }
}

// ---------------------------------------------------------------------------
// Fallback (tiny ws): fp32, direct x reads (round 1, correct for any ws).
// ---------------------------------------------------------------------------
__global__ __launch_bounds__(256, 4) void lc2d_fallback(
    const float* __restrict__ x, const float* __restrict__ weight,
    const float* __restrict__ bias, float* __restrict__ out) {
  int t0 = blockIdx.x;
  int loc = ((t0 & 7) << 7) | (t0 >> 3);
  int h = loc >> 5, w = loc & 31;
  int tid = threadIdx.x;
  int b = tid & 63;
  int o0 = (tid >> 6) * 16;
  __shared__ float As[72 * 64];
  float acc[16];
  #pragma unroll
  for (int j = 0; j < 16; ++j) acc[j] = bias[(size_t)(o0 + j) * NLOC + loc];
  for (int ic = 0; ic < 8; ++ic) {
    __syncthreads();
    #pragma unroll
    for (int s = 0; s < 18; ++s) {
      int f = s * 256 + tid;
      int k = f >> 6, lb = f & 63;
      int kk = k >> 3, isub = k & 7;
      int i = ic * 8 + isub;
      int kh = kk / 3, kw = kk - kh * 3;
      int hh = h + kh - 1, ww = w + kw - 1;
      float v = (hh >= 0 && hh < HW_ && ww >= 0 && ww < HW_)
                  ? x[(((size_t)lb * 64 + i) * HW_ + hh) * HW_ + ww] : 0.f;
      As[k * 64 + lb] = v;
    }
    __syncthreads();
    #pragma unroll 1
    for (int isub = 0; isub < 8; ++isub) {
      const float* wp = weight + (size_t)(ic * 8 + isub) * W_IST
                               + (size_t)o0 * W_OST + loc * 9;
      #pragma unroll
      for (int kk = 0; kk < 9; ++kk) {
        float a = As[(kk * 8 + isub) * 64 + b];
        #pragma unroll
        for (int j = 0; j < 16; ++j)
          acc[j] = fmaf(a, wp[(size_t)j * W_OST + kk], acc[j]);
      }
    }
  }
  size_t ob = ((size_t)b * 64 + o0) * NLOC + loc;
  #pragma unroll
  for (int j = 0; j < 16; ++j) out[ob + (size_t)j * NLOC] = acc[j];
}

// ---------------------------------------------------------------------------
extern "C" void kernel_launch(void* const* d_in, const int* in_sizes, int n_in,
                              void* d_out, int out_size, void* d_ws, size_t ws_size,
                              hipStream_t stream) {
  const float* x  = (const float*)d_in[0];
  const float* wt = (const float*)d_in[1];
  const float* bs = (const float*)d_in[2];
  float* out = (float*)d_out;

  if (ws_size >= WS_NEED) {
    unsigned short* xtb = (unsigned short*)d_ws;
    xpose_pad<<<64 * HP_, 256, 0, stream>>>(x, xtb);
    lc2d_fused<<<1024, 256, 0, stream>>>(xtb, wt, bs, out);
  } else {
    lc2d_fallback<<<NLOC, 256, 0, stream>>>(x, wt, bs, out);
  }
}

// Round 9
// 265.864 us; speedup vs baseline: 1.0237x; 1.0237x over previous
//
#include <hip/hip_runtime.h>
#include <hip/hip_bf16.h>

// LocallyConnected2d: y[b,o,h,w] = bias[o,h,w] +
//   sum_{i,kh,kw} xpad[b,i,h+kh,w+kw] * weight[i,o,h,w,kh,kw]
// B=64, CIN=COUT=64, H=W=32, K=3, pad=1, fp32 in/out.
// Round 14: COALESCED weight staging at o-quarter scale. Round 13 proved the
// bottleneck is TD line-lookup throughput (per-lane B loads = 64 lines/instr;
// occupancy 2x'd with zero speedup). Return to round-7's verified coalesced
// granule scheme, halved: per chunk stage 4i x 16o x 4loc x 9kk = 576 float4
// via ~2.25 coalesced float4/thread (144B granules), f2bf + 9-elem scatter
// to double-buffered Bf (4KB) / Bs (kk=8, round-13 layout). One soft barrier
// per chunk. A-path scr-direct (verified r10-r13) unchanged. LDS 33KB,
// grid 1024 -> 4 blocks/CU. All mappings are verified pieces recombined.

#define B_    64
#define HW_   32
#define HP_   34
#define NLOC  1024
#define W_OST 9216u     // floats per o step
#define W_IST 589824u   // floats per i step
#define XT_BYTES  ((size_t)64*HP_*HP_*64*2)          //  9,469,952
#define WS_NEED   (XT_BYTES)
#define SCR_R 528       // shorts per role stripe: 512 + 16 pad (bank spread)

typedef __attribute__((ext_vector_type(8))) short short8;
typedef __attribute__((ext_vector_type(8))) unsigned short ushort8;
typedef __attribute__((ext_vector_type(4))) float floatx4;

static __device__ __forceinline__ unsigned short f2bf(float f) {
  __hip_bfloat16 h = __float2bfloat16(f);   // RNE
  return __builtin_bit_cast(unsigned short, h);
}

// soft workgroup barrier: drain LDS only, keep VMEM loads in flight
static __device__ __forceinline__ void soft_barrier() {
  __asm__ volatile("s_waitcnt lgkmcnt(0)" ::: "memory");
  __builtin_amdgcn_s_barrier();
}

// ---------------------------------------------------------------------------
// Kernel 1: pad+transpose x[b][i][h][w] (fp32) -> xt[i][hh][ww][b] (bf16).
// (verified rounds 2-13, unchanged)
// ---------------------------------------------------------------------------
__global__ __launch_bounds__(256) void xpose_pad(const float* __restrict__ x,
                                                 unsigned short* __restrict__ xt) {
  int bid = blockIdx.x;                 // 64*34
  int i = bid / HP_, hh = bid % HP_;
  __shared__ float tile[B_ * 33];
  int t = threadIdx.x;
  bool interior = (hh >= 1 && hh <= HW_);
  if (interior) {
    int h = hh - 1, w = t & 31, bs = t >> 5;
    #pragma unroll
    for (int r = 0; r < 8; ++r) {
      int b = r * 8 + bs;
      tile[b * 33 + w] = x[(((size_t)b * 64 + i) * HW_ + h) * HW_ + w];
    }
  }
  __syncthreads();
  int b = t & 63, wsb = t >> 6;
  size_t base = (size_t)(i * HP_ + hh) * HP_ * B_;
  #pragma unroll
  for (int s = 0; s < 9; ++s) {
    int ww = s * 4 + wsb;
    if (ww < HP_) {
      float v = 0.f;
      if (interior && ww >= 1 && ww <= HW_) v = tile[b * 33 + (ww - 1)];
      xt[base + (size_t)ww * B_ + b] = f2bf(v);
    }
  }
}

// ---------------------------------------------------------------------------
// Kernel 2: fused im2col + weight-stage + GEMM, o-quarter split.
// Block = 4 consecutive locs x 16 o's, 256 thr = 4 waves; wave = ll (loc).
// LDS: Bf 2x4K + Bs 8K + scr4 16.9K = 32.9K -> 4 blocks/CU.
// ---------------------------------------------------------------------------
__global__ __launch_bounds__(256, 2) void lc2d_fused(
    const unsigned short* __restrict__ xt,
    const float* __restrict__ wsrc,
    const float* __restrict__ bias,
    float* __restrict__ out) {
  __shared__ __align__(16) unsigned short Bf[2][4 * 64 * 8];   // 2 x 4 KB
  __shared__ __align__(16) unsigned short Bs[8 * 64 * 8];      // 8 KB (kk=8)
  __shared__ __align__(16) unsigned short scr4[4][4 * SCR_R];  // 16.9 KB

  const int bid   = blockIdx.x;                    // 1024 blocks
  const int lt    = ((bid & 7) << 7) | (bid >> 3); // XCD-grouped tile id
  const int oq    = lt & 3;                        // o-quarter 0..3
  const int loc0  = (lt >> 2) << 2;                // loc0 % 4 == 0
  const int tid   = threadIdx.x;
  const int lane  = tid & 63;
  const int ll    = tid >> 6;                      // wave = loc index 0..3
  const int loc   = loc0 + ll;
  const int hblk  = loc >> 5, wblk = loc & 31;
  const int col   = lane & 15;
  const int quad  = lane >> 4;
  const int o_0   = oq * 16 + col;

  floatx4 acc[4];
  {
    float b0 = bias[(unsigned)o_0 * 1024u + (unsigned)loc];
    #pragma unroll
    for (int mt = 0; mt < 4; ++mt) acc[mt] = (floatx4){b0, b0, b0, b0};
  }

  // ---- weight staging: 576 float4 per chunk (4i x 16o x 4loc x 9kk),
  //      round-7 verified granule scheme at o-quarter scale.
  floatx4 wa[3], wb[3];                        // depth-2: two named sets
  const bool lastok = (tid < 64);              // r==2 covers idx 512..575
  const size_t wrow = (size_t)loc0 * 9;        // 16B-aligned (loc0 % 4 == 0)
  const unsigned obase = (unsigned)oq * 16u;

  auto issueW = [&](int c, floatx4 (&wreg)[3]) {
    const int i0 = c << 2;
    #pragma unroll
    for (int r = 0; r < 3; ++r) {
      if (r < 2 || lastok) {
        int idx = r * 256 + tid;
        int g = idx / 9, p = idx - g * 9;      // granule, float4-pos
        int i = i0 + (g >> 4), o = (int)obase + (g & 15);
        wreg[r] = *(const floatx4*)(wsrc + (size_t)i * W_IST + (size_t)o * W_OST
                                    + wrow + (size_t)(p * 4));
      }
    }
  };
  auto scatterW = [&](int c, floatx4 (&wreg)[3], unsigned short* bfp) {
    const int i0 = c << 2;
    #pragma unroll
    for (int r = 0; r < 3; ++r) {
      if (r < 2 || lastok) {
        int idx = r * 256 + tid;
        int g = idx / 9, p = idx - g * 9;
        int iq = g >> 4, oc = g & 15;
        int flane = iq * 16 + oc;              // B-frag lane: quad=iq, col=oc
        #pragma unroll
        for (int e = 0; e < 4; ++e) {
          int fi = p * 4 + e;                  // 0..35 within granule
          int lle = fi / 9, kk = fi - lle * 9;
          unsigned short v = f2bf(wreg[r][e]);
          if (kk < 8) {
            bfp[(lle * 64 + flane) * 8 + kk] = v;
          } else {                             // kk == 8 -> Bs (r13 layout)
            int i = i0 + iq;
            int sc = i >> 5, k2 = i & 31;
            Bs[((lle * 2 + sc) * 64 + (k2 >> 3) * 16 + oc) * 8 + (k2 & 7)] = v;
          }
        }
      }
    }
  };

  // ---- A side: xt load + 4-role scr + direct reg gather (verified r10-r13)
  auto xtLoad = [&](int t, int q) -> ushort8 {
    int i, kh, kw;
    if (t < 16) {
      i = (t << 2) + q;
      int kk = lane >> 3;                      // 0..7
      kh = kk / 3; kw = kk - kh * 3;
    } else {
      i = ((t - 16) << 5) + (q << 3) + (lane >> 3);
      kh = 2; kw = 2;
    }
    return *(const ushort8*)(xt +
        (((unsigned)i * HP_ + (unsigned)(hblk + kh)) * HP_ + (unsigned)(wblk + kw)) * 64u
        + ((unsigned)(lane & 7) << 3));
  };
  auto buildA = [&](ushort8 v0, ushort8 v1, ushort8 v2, ushort8 v3,
                    ushort8 &a0, ushort8 &a1, ushort8 &a2, ushort8 &a3) {
    *(ushort8*)&scr4[ll][0 * SCR_R + (lane << 3)] = v0;
    *(ushort8*)&scr4[ll][1 * SCR_R + (lane << 3)] = v1;
    *(ushort8*)&scr4[ll][2 * SCR_R + (lane << 3)] = v2;
    *(ushort8*)&scr4[ll][3 * SCR_R + (lane << 3)] = v3;
    __asm__ volatile("s_waitcnt lgkmcnt(0)" ::: "memory");
    const int rb = (lane >> 4) * SCR_R + (lane & 15);
    #pragma unroll
    for (int j = 0; j < 8; ++j) {
      a0[j] = scr4[ll][rb + j * 64 +  0];
      a1[j] = scr4[ll][rb + j * 64 + 16];
      a2[j] = scr4[ll][rb + j * 64 + 32];
      a3[j] = scr4[ll][rb + j * 64 + 48];
    }
  };

  // ---- MFMA: 4 A-frags x 1 B-frag (same call order as verified r13)
  auto doMFMA = [&](ushort8 a0, ushort8 a1, ushort8 a2, ushort8 a3, ushort8 b0) {
    acc[0] = __builtin_amdgcn_mfma_f32_16x16x32_bf16(
        __builtin_bit_cast(short8, a0), __builtin_bit_cast(short8, b0), acc[0], 0, 0, 0);
    acc[1] = __builtin_amdgcn_mfma_f32_16x16x32_bf16(
        __builtin_bit_cast(short8, a1), __builtin_bit_cast(short8, b0), acc[1], 0, 0, 0);
    acc[2] = __builtin_amdgcn_mfma_f32_16x16x32_bf16(
        __builtin_bit_cast(short8, a2), __builtin_bit_cast(short8, b0), acc[2], 0, 0, 0);
    acc[3] = __builtin_amdgcn_mfma_f32_16x16x32_bf16(
        __builtin_bit_cast(short8, a3), __builtin_bit_cast(short8, b0), acc[3], 0, 0, 0);
  };

  // ---- prologue: chunk 0 A+B staged, chunk 1 weights issued
  issueW(0, wa);
  ushort8 a0, a1, a2, a3;
  {
    ushort8 xv0 = xtLoad(0, 0), xv1 = xtLoad(0, 1);
    ushort8 xv2 = xtLoad(0, 2), xv3 = xtLoad(0, 3);
    scatterW(0, wa, &Bf[0][0]);
    issueW(1, wb);
    buildA(xv0, xv1, xv2, xv3, a0, a1, a2, a3);
  }
  soft_barrier();

  // ---- main loop c = 0..15 (unrolled x2 so wa/wb indexing is static)
#define STEP(C, WI, WS) do {                                                  \
    const int c_ = (C);                                                       \
    ushort8 nx0 = xtLoad(c_ + 1, 0), nx1 = xtLoad(c_ + 1, 1);                 \
    ushort8 nx2 = xtLoad(c_ + 1, 2), nx3 = xtLoad(c_ + 1, 3);                 \
    if (c_ + 2 <= 15) issueW(c_ + 2, WI);                                     \
    ushort8 b0 = *(const ushort8*)(&Bf[c_ & 1][0]                             \
                                   + (size_t)(ll * 64 + lane) * 8);           \
    doMFMA(a0, a1, a2, a3, b0);                                               \
    buildA(nx0, nx1, nx2, nx3, a0, a1, a2, a3);  /* A for c_+1 */             \
    if (c_ + 1 <= 15) scatterW(c_ + 1, WS, &Bf[(c_ & 1) ^ 1][0]);             \
    soft_barrier();                                                           \
  } while (0)

  #pragma unroll 1
  for (int cc = 0; cc < 16; cc += 2) {
    STEP(cc,     wa, wb);   // even c: issue->wa, scatter<-wb
    STEP(cc + 1, wb, wa);   // odd  c: issue->wb, scatter<-wa
  }
#undef STEP

  // ---- stash chunks (kk=8): c = 16, 17; B from Bs (all scatters barrier'd;
  //      a0..a3 currently hold chunk-16's A from iteration 15's buildA)
  {
    ushort8 nx0 = xtLoad(17, 0), nx1 = xtLoad(17, 1);
    ushort8 nx2 = xtLoad(17, 2), nx3 = xtLoad(17, 3);
    {
      ushort8 b0 = *(const ushort8*)(&Bs[0] + (size_t)(((ll << 1) + 0) * 64 + lane) * 8);
      doMFMA(a0, a1, a2, a3, b0);                              // sc=0
    }
    buildA(nx0, nx1, nx2, nx3, a0, a1, a2, a3);
    {
      ushort8 b0 = *(const ushort8*)(&Bs[0] + (size_t)(((ll << 1) + 1) * 64 + lane) * 8);
      doMFMA(a0, a1, a2, a3, b0);                              // sc=1
    }
  }

  // ---- epilogue: D mapping col=o=lane&15, row=b = mt*16 + quad*4 + r (verified)
  #pragma unroll
  for (int mt = 0; mt < 4; ++mt) {
    int b = mt * 16 + quad * 4;
    #pragma unroll
    for (int r = 0; r < 4; ++r) {
      out[((unsigned)(b + r) * 64u + (unsigned)o_0) * 1024u + (unsigned)loc] = acc[mt][r];
    }
  }
}

// ---------------------------------------------------------------------------
// Fallback (tiny ws): fp32, direct x reads (round 1, correct for any ws).
// ---------------------------------------------------------------------------
__global__ __launch_bounds__(256, 4) void lc2d_fallback(
    const float* __restrict__ x, const float* __restrict__ weight,
    const float* __restrict__ bias, float* __restrict__ out) {
  int t0 = blockIdx.x;
  int loc = ((t0 & 7) << 7) | (t0 >> 3);
  int h = loc >> 5, w = loc & 31;
  int tid = threadIdx.x;
  int b = tid & 63;
  int o0 = (tid >> 6) * 16;
  __shared__ float As[72 * 64];
  float acc[16];
  #pragma unroll
  for (int j = 0; j < 16; ++j) acc[j] = bias[(size_t)(o0 + j) * NLOC + loc];
  for (int ic = 0; ic < 8; ++ic) {
    __syncthreads();
    #pragma unroll
    for (int s = 0; s < 18; ++s) {
      int f = s * 256 + tid;
      int k = f >> 6, lb = f & 63;
      int kk = k >> 3, isub = k & 7;
      int i = ic * 8 + isub;
      int kh = kk / 3, kw = kk - kh * 3;
      int hh = h + kh - 1, ww = w + kw - 1;
      float v = (hh >= 0 && hh < HW_ && ww >= 0 && ww < HW_)
                  ? x[(((size_t)lb * 64 + i) * HW_ + hh) * HW_ + ww] : 0.f;
      As[k * 64 + lb] = v;
    }
    __syncthreads();
    #pragma unroll 1
    for (int isub = 0; isub < 8; ++isub) {
      const float* wp = weight + (size_t)(ic * 8 + isub) * W_IST
                               + (size_t)o0 * W_OST + loc * 9;
      #pragma unroll
      for (int kk = 0; kk < 9; ++kk) {
        float a = As[(kk * 8 + isub) * 64 + b];
        #pragma unroll
        for (int j = 0; j < 16; ++j)
          acc[j] = fmaf(a, wp[(size_t)j * W_OST + kk], acc[j]);
      }
    }
  }
  size_t ob = ((size_t)b * 64 + o0) * NLOC + loc;
  #pragma unroll
  for (int j = 0; j < 16; ++j) out[ob + (size_t)j * NLOC] = acc[j];
}

// ---------------------------------------------------------------------------
extern "C" void kernel_launch(void* const* d_in, const int* in_sizes, int n_in,
                              void* d_out, int out_size, void* d_ws, size_t ws_size,
                              hipStream_t stream) {
  const float* x  = (const float*)d_in[0];
  const float* wt = (const float*)d_in[1];
  const float* bs = (const float*)d_in[2];
  float* out = (float*)d_out;

  if (ws_size >= WS_NEED) {
    unsigned short* xtb = (unsigned short*)d_ws;
    xpose_pad<<<64 * HP_, 256, 0, stream>>>(x, xtb);
    lc2d_fused<<<1024, 256, 0, stream>>>(xtb, wt, bs, out);
  } else {
    lc2d_fallback<<<NLOC, 256, 0, stream>>>(x, wt, bs, out);
  }
}

// Round 10
// 260.022 us; speedup vs baseline: 1.0467x; 1.0225x over previous
//
#include <hip/hip_runtime.h>
#include <hip/hip_bf16.h>

// LocallyConnected2d: y[b,o,h,w] = bias[o,h,w] +
//   sum_{i,kh,kw} xpad[b,i,h+kh,w+kw] * weight[i,o,h,w,kh,kw]
// B=64, CIN=COUT=64, H=W=32, K=3, pad=1, fp32 in/out.
// Round 15: pure RESCHEDULE of the verified round-14 kernel (95us fused).
// Quad-buffered Bf + barrier every 2 chunks (18 -> 9 barriers), scatter ->
// consume slack 1 -> 2 iterations. At iter c: issue(c+3), consume Bf[c&3],
// buildA(c+1), scatter(c+2)->Bf[(c+2)&3]; barrier after odd c.
// Safety: Bf[X] rewritten (chunk c+4, iter c+2) >= 1 barrier after last
// read (chunk c, iter c) for both parities; Bs complete by iter 13.
// All data mappings bit-identical to round 14 (passed, absmax 0.5).

#define B_    64
#define HW_   32
#define HP_   34
#define NLOC  1024
#define W_OST 9216u     // floats per o step
#define W_IST 589824u   // floats per i step
#define XT_BYTES  ((size_t)64*HP_*HP_*64*2)          //  9,469,952
#define WS_NEED   (XT_BYTES)
#define SCR_R 528       // shorts per role stripe: 512 + 16 pad (bank spread)

typedef __attribute__((ext_vector_type(8))) short short8;
typedef __attribute__((ext_vector_type(8))) unsigned short ushort8;
typedef __attribute__((ext_vector_type(4))) float floatx4;

static __device__ __forceinline__ unsigned short f2bf(float f) {
  __hip_bfloat16 h = __float2bfloat16(f);   // RNE
  return __builtin_bit_cast(unsigned short, h);
}

// soft workgroup barrier: drain LDS only, keep VMEM loads in flight
static __device__ __forceinline__ void soft_barrier() {
  __asm__ volatile("s_waitcnt lgkmcnt(0)" ::: "memory");
  __builtin_amdgcn_s_barrier();
}

// ---------------------------------------------------------------------------
// Kernel 1: pad+transpose x[b][i][h][w] (fp32) -> xt[i][hh][ww][b] (bf16).
// (verified rounds 2-14, unchanged)
// ---------------------------------------------------------------------------
__global__ __launch_bounds__(256) void xpose_pad(const float* __restrict__ x,
                                                 unsigned short* __restrict__ xt) {
  int bid = blockIdx.x;                 // 64*34
  int i = bid / HP_, hh = bid % HP_;
  __shared__ float tile[B_ * 33];
  int t = threadIdx.x;
  bool interior = (hh >= 1 && hh <= HW_);
  if (interior) {
    int h = hh - 1, w = t & 31, bs = t >> 5;
    #pragma unroll
    for (int r = 0; r < 8; ++r) {
      int b = r * 8 + bs;
      tile[b * 33 + w] = x[(((size_t)b * 64 + i) * HW_ + h) * HW_ + w];
    }
  }
  __syncthreads();
  int b = t & 63, wsb = t >> 6;
  size_t base = (size_t)(i * HP_ + hh) * HP_ * B_;
  #pragma unroll
  for (int s = 0; s < 9; ++s) {
    int ww = s * 4 + wsb;
    if (ww < HP_) {
      float v = 0.f;
      if (interior && ww >= 1 && ww <= HW_) v = tile[b * 33 + (ww - 1)];
      xt[base + (size_t)ww * B_ + b] = f2bf(v);
    }
  }
}

// ---------------------------------------------------------------------------
// Kernel 2: fused im2col + weight-stage + GEMM, o-quarter split.
// Block = 4 consecutive locs x 16 o's, 256 thr = 4 waves; wave = ll (loc).
// LDS: Bf 4x4K + Bs 8K + scr4 16.9K = 40.9K.
// ---------------------------------------------------------------------------
__global__ __launch_bounds__(256, 2) void lc2d_fused(
    const unsigned short* __restrict__ xt,
    const float* __restrict__ wsrc,
    const float* __restrict__ bias,
    float* __restrict__ out) {
  __shared__ __align__(16) unsigned short Bf[4][4 * 64 * 8];   // 4 x 4 KB
  __shared__ __align__(16) unsigned short Bs[8 * 64 * 8];      // 8 KB (kk=8)
  __shared__ __align__(16) unsigned short scr4[4][4 * SCR_R];  // 16.9 KB

  const int bid   = blockIdx.x;                    // 1024 blocks
  const int lt    = ((bid & 7) << 7) | (bid >> 3); // XCD-grouped tile id
  const int oq    = lt & 3;                        // o-quarter 0..3
  const int loc0  = (lt >> 2) << 2;                // loc0 % 4 == 0
  const int tid   = threadIdx.x;
  const int lane  = tid & 63;
  const int ll    = tid >> 6;                      // wave = loc index 0..3
  const int loc   = loc0 + ll;
  const int hblk  = loc >> 5, wblk = loc & 31;
  const int col   = lane & 15;
  const int quad  = lane >> 4;
  const int o_0   = oq * 16 + col;

  floatx4 acc[4];
  {
    float b0 = bias[(unsigned)o_0 * 1024u + (unsigned)loc];
    #pragma unroll
    for (int mt = 0; mt < 4; ++mt) acc[mt] = (floatx4){b0, b0, b0, b0};
  }

  // ---- weight staging: 576 float4 per chunk (4i x 16o x 4loc x 9kk),
  //      verbatim round-14 (verified) granule scheme.
  floatx4 wa[3], wb[3];                        // depth-2: two named sets
  const bool lastok = (tid < 64);              // r==2 covers idx 512..575
  const size_t wrow = (size_t)loc0 * 9;        // 16B-aligned (loc0 % 4 == 0)
  const unsigned obase = (unsigned)oq * 16u;

  auto issueW = [&](int c, floatx4 (&wreg)[3]) {
    const int i0 = c << 2;
    #pragma unroll
    for (int r = 0; r < 3; ++r) {
      if (r < 2 || lastok) {
        int idx = r * 256 + tid;
        int g = idx / 9, p = idx - g * 9;      // granule, float4-pos
        int i = i0 + (g >> 4), o = (int)obase + (g & 15);
        wreg[r] = *(const floatx4*)(wsrc + (size_t)i * W_IST + (size_t)o * W_OST
                                    + wrow + (size_t)(p * 4));
      }
    }
  };
  auto scatterW = [&](int c, floatx4 (&wreg)[3], unsigned short* bfp) {
    const int i0 = c << 2;
    #pragma unroll
    for (int r = 0; r < 3; ++r) {
      if (r < 2 || lastok) {
        int idx = r * 256 + tid;
        int g = idx / 9, p = idx - g * 9;
        int iq = g >> 4, oc = g & 15;
        int flane = iq * 16 + oc;              // B-frag lane: quad=iq, col=oc
        #pragma unroll
        for (int e = 0; e < 4; ++e) {
          int fi = p * 4 + e;                  // 0..35 within granule
          int lle = fi / 9, kk = fi - lle * 9;
          unsigned short v = f2bf(wreg[r][e]);
          if (kk < 8) {
            bfp[(lle * 64 + flane) * 8 + kk] = v;
          } else {                             // kk == 8 -> Bs (r13 layout)
            int i = i0 + iq;
            int sc = i >> 5, k2 = i & 31;
            Bs[((lle * 2 + sc) * 64 + (k2 >> 3) * 16 + oc) * 8 + (k2 & 7)] = v;
          }
        }
      }
    }
  };

  // ---- A side: xt load + 4-role scr + direct reg gather (verified r10-r14)
  auto xtLoad = [&](int t, int q) -> ushort8 {
    int i, kh, kw;
    if (t < 16) {
      i = (t << 2) + q;
      int kk = lane >> 3;                      // 0..7
      kh = kk / 3; kw = kk - kh * 3;
    } else {
      i = ((t - 16) << 5) + (q << 3) + (lane >> 3);
      kh = 2; kw = 2;
    }
    return *(const ushort8*)(xt +
        (((unsigned)i * HP_ + (unsigned)(hblk + kh)) * HP_ + (unsigned)(wblk + kw)) * 64u
        + ((unsigned)(lane & 7) << 3));
  };
  auto buildA = [&](ushort8 v0, ushort8 v1, ushort8 v2, ushort8 v3,
                    ushort8 &a0, ushort8 &a1, ushort8 &a2, ushort8 &a3) {
    *(ushort8*)&scr4[ll][0 * SCR_R + (lane << 3)] = v0;
    *(ushort8*)&scr4[ll][1 * SCR_R + (lane << 3)] = v1;
    *(ushort8*)&scr4[ll][2 * SCR_R + (lane << 3)] = v2;
    *(ushort8*)&scr4[ll][3 * SCR_R + (lane << 3)] = v3;
    __asm__ volatile("s_waitcnt lgkmcnt(0)" ::: "memory");
    const int rb = (lane >> 4) * SCR_R + (lane & 15);
    #pragma unroll
    for (int j = 0; j < 8; ++j) {
      a0[j] = scr4[ll][rb + j * 64 +  0];
      a1[j] = scr4[ll][rb + j * 64 + 16];
      a2[j] = scr4[ll][rb + j * 64 + 32];
      a3[j] = scr4[ll][rb + j * 64 + 48];
    }
  };

  // ---- MFMA: 4 A-frags x 1 B-frag (same call order as verified r13/r14)
  auto doMFMA = [&](ushort8 a0, ushort8 a1, ushort8 a2, ushort8 a3, ushort8 b0) {
    acc[0] = __builtin_amdgcn_mfma_f32_16x16x32_bf16(
        __builtin_bit_cast(short8, a0), __builtin_bit_cast(short8, b0), acc[0], 0, 0, 0);
    acc[1] = __builtin_amdgcn_mfma_f32_16x16x32_bf16(
        __builtin_bit_cast(short8, a1), __builtin_bit_cast(short8, b0), acc[1], 0, 0, 0);
    acc[2] = __builtin_amdgcn_mfma_f32_16x16x32_bf16(
        __builtin_bit_cast(short8, a2), __builtin_bit_cast(short8, b0), acc[2], 0, 0, 0);
    acc[3] = __builtin_amdgcn_mfma_f32_16x16x32_bf16(
        __builtin_bit_cast(short8, a3), __builtin_bit_cast(short8, b0), acc[3], 0, 0, 0);
  };

  // ---- prologue: chunks 0,1 staged; chunk 2 weights in flight; chunk-0 A.
  issueW(0, wa);
  issueW(1, wb);
  ushort8 a0, a1, a2, a3;
  {
    ushort8 xv0 = xtLoad(0, 0), xv1 = xtLoad(0, 1);
    ushort8 xv2 = xtLoad(0, 2), xv3 = xtLoad(0, 3);
    scatterW(0, wa, &Bf[0][0]);
    buildA(xv0, xv1, xv2, xv3, a0, a1, a2, a3);
    scatterW(1, wb, &Bf[1][0]);
    issueW(2, wa);
  }
  soft_barrier();

  // ---- main loop: 8 pairs; per iter c: issue(c+3), MFMA(Bf[c&3]),
  //      buildA(c+1), scatter(c+2 -> Bf[(c+2)&3]); barrier after odd c.
#define SUBSTEP(C, WI, WS) do {                                               \
    const int c_ = (C);                                                       \
    ushort8 nx0 = xtLoad(c_ + 1, 0), nx1 = xtLoad(c_ + 1, 1);                 \
    ushort8 nx2 = xtLoad(c_ + 1, 2), nx3 = xtLoad(c_ + 1, 3);                 \
    if (c_ + 3 <= 15) issueW(c_ + 3, WI);                                     \
    ushort8 b0 = *(const ushort8*)(&Bf[c_ & 3][0]                             \
                                   + (size_t)(ll * 64 + lane) * 8);           \
    doMFMA(a0, a1, a2, a3, b0);                                               \
    buildA(nx0, nx1, nx2, nx3, a0, a1, a2, a3);  /* A for c_+1 */             \
    if (c_ + 2 <= 15) scatterW(c_ + 2, WS, &Bf[(c_ + 2) & 3][0]);             \
  } while (0)

  #pragma unroll 1
  for (int cc = 0; cc < 16; cc += 2) {
    SUBSTEP(cc,     wb, wa);   // even c: issue->wb, scatter<-wa
    SUBSTEP(cc + 1, wa, wb);   // odd  c: issue->wa, scatter<-wb
    soft_barrier();
  }
#undef SUBSTEP

  // ---- stash chunks (kk=8): c = 16, 17; B from Bs (all scatters barrier'd;
  //      a0..a3 hold chunk-16's A from iteration 15's buildA)
  {
    ushort8 nx0 = xtLoad(17, 0), nx1 = xtLoad(17, 1);
    ushort8 nx2 = xtLoad(17, 2), nx3 = xtLoad(17, 3);
    {
      ushort8 b0 = *(const ushort8*)(&Bs[0] + (size_t)(((ll << 1) + 0) * 64 + lane) * 8);
      doMFMA(a0, a1, a2, a3, b0);                              // sc=0
    }
    buildA(nx0, nx1, nx2, nx3, a0, a1, a2, a3);
    {
      ushort8 b0 = *(const ushort8*)(&Bs[0] + (size_t)(((ll << 1) + 1) * 64 + lane) * 8);
      doMFMA(a0, a1, a2, a3, b0);                              // sc=1
    }
  }

  // ---- epilogue: D mapping col=o=lane&15, row=b = mt*16 + quad*4 + r (verified)
  #pragma unroll
  for (int mt = 0; mt < 4; ++mt) {
    int b = mt * 16 + quad * 4;
    #pragma unroll
    for (int r = 0; r < 4; ++r) {
      out[((unsigned)(b + r) * 64u + (unsigned)o_0) * 1024u + (unsigned)loc] = acc[mt][r];
    }
  }
}

// ---------------------------------------------------------------------------
// Fallback (tiny ws): fp32, direct x reads (round 1, correct for any ws).
// ---------------------------------------------------------------------------
__global__ __launch_bounds__(256, 4) void lc2d_fallback(
    const float* __restrict__ x, const float* __restrict__ weight,
    const float* __restrict__ bias, float* __restrict__ out) {
  int t0 = blockIdx.x;
  int loc = ((t0 & 7) << 7) | (t0 >> 3);
  int h = loc >> 5, w = loc & 31;
  int tid = threadIdx.x;
  int b = tid & 63;
  int o0 = (tid >> 6) * 16;
  __shared__ float As[72 * 64];
  float acc[16];
  #pragma unroll
  for (int j = 0; j < 16; ++j) acc[j] = bias[(size_t)(o0 + j) * NLOC + loc];
  for (int ic = 0; ic < 8; ++ic) {
    __syncthreads();
    #pragma unroll
    for (int s = 0; s < 18; ++s) {
      int f = s * 256 + tid;
      int k = f >> 6, lb = f & 63;
      int kk = k >> 3, isub = k & 7;
      int i = ic * 8 + isub;
      int kh = kk / 3, kw = kk - kh * 3;
      int hh = h + kh - 1, ww = w + kw - 1;
      float v = (hh >= 0 && hh < HW_ && ww >= 0 && ww < HW_)
                  ? x[(((size_t)lb * 64 + i) * HW_ + hh) * HW_ + ww] : 0.f;
      As[k * 64 + lb] = v;
    }
    __syncthreads();
    #pragma unroll 1
    for (int isub = 0; isub < 8; ++isub) {
      const float* wp = weight + (size_t)(ic * 8 + isub) * W_IST
                               + (size_t)o0 * W_OST + loc * 9;
      #pragma unroll
      for (int kk = 0; kk < 9; ++kk) {
        float a = As[(kk * 8 + isub) * 64 + b];
        #pragma unroll
        for (int j = 0; j < 16; ++j)
          acc[j] = fmaf(a, wp[(size_t)j * W_OST + kk], acc[j]);
      }
    }
  }
  size_t ob = ((size_t)b * 64 + o0) * NLOC + loc;
  #pragma unroll
  for (int j = 0; j < 16; ++j) out[ob + (size_t)j * NLOC] = acc[j];
}

// ---------------------------------------------------------------------------
extern "C" void kernel_launch(void* const* d_in, const int* in_sizes, int n_in,
                              void* d_out, int out_size, void* d_ws, size_t ws_size,
                              hipStream_t stream) {
  const float* x  = (const float*)d_in[0];
  const float* wt = (const float*)d_in[1];
  const float* bs = (const float*)d_in[2];
  float* out = (float*)d_out;

  if (ws_size >= WS_NEED) {
    unsigned short* xtb = (unsigned short*)d_ws;
    xpose_pad<<<64 * HP_, 256, 0, stream>>>(x, xtb);
    lc2d_fused<<<1024, 256, 0, stream>>>(xtb, wt, bs, out);
  } else {
    lc2d_fallback<<<NLOC, 256, 0, stream>>>(x, wt, bs, out);
  }
}